// Round 7
// baseline (282.220 us; speedup 1.0000x reference)
//
#include <hip/hip_runtime.h>

typedef unsigned short ushort_t;
typedef _Float16 half_t;
typedef __attribute__((ext_vector_type(8))) unsigned short ushort8;
typedef __attribute__((ext_vector_type(8))) _Float16 half8;
typedef __attribute__((ext_vector_type(8))) short bf16x8;
typedef __attribute__((ext_vector_type(4))) float f32x4;

#define BB 64
#define II 512
#define DD 128
#define NN 32
#define OO 64

__device__ inline ushort_t f2bf(float f) {
  unsigned int u = __float_as_uint(f);
  u += 0x7FFF + ((u >> 16) & 1);   // RNE
  return (ushort_t)(u >> 16);
}
__device__ inline float bf2f(ushort_t h) {
  return __uint_as_float(((unsigned int)h) << 16);
}

// load 8 contiguous u-elements (fp16) as fp32
__device__ inline void load8u(const half_t* p, float* a) {
  half8 v = *(const half8*)p;
  #pragma unroll
  for (int e = 0; e < 8; ++e) a[e] = (float)v[e];
}

// ---------------------------------------------------------------------------
// K1: u[b,n,i,o] = sum_d x[b,i,d]*W[n,i,o,d] (split-bf16 MFMA, fp32-accurate),
// u stored fp16; FUSED round-0 partial: acc0[n] += acc across the block's 8 i,
// written to part0[ic][b][n][o] (fp32) -> k_reduce0 builds out0.
// Grid (64 i-chunks, 8 n-quads) = 512 blocks, 2/CU. Each (n,i) W-tile staged
// exactly once -> W HBM traffic unchanged.
// ---------------------------------------------------------------------------
__global__ __launch_bounds__(256, 2) void k_compute_u_r0(
    const float* __restrict__ x, const float* __restrict__ W,
    half_t* __restrict__ u, float* __restrict__ part0)
{
  __shared__ ushort_t Ah[64*128] __attribute__((aligned(16)));
  __shared__ ushort_t Al[64*128] __attribute__((aligned(16)));
  __shared__ ushort_t Bh[64*128] __attribute__((aligned(16)));
  __shared__ ushort_t Bl[64*128] __attribute__((aligned(16)));
  __shared__ float    Cs[64*64]  __attribute__((aligned(16)));
  const int tid  = threadIdx.x;
  const int ic   = blockIdx.x;       // i0 = ic*8
  const int nj   = blockIdx.y;       // n0 = nj*4
  const int w    = tid >> 6;
  const int lane = tid & 63;

  f32x4 acc0[4][4];
  #pragma unroll
  for (int j = 0; j < 4; ++j)
    #pragma unroll
    for (int ot = 0; ot < 4; ++ot) acc0[j][ot] = {0.f, 0.f, 0.f, 0.f};

  #pragma unroll 1
  for (int it = 0; it < 8; ++it) {
    const int i = ic*8 + it;
    // stage A = x[:, i, :] (prev readers done via last bar of prev j-loop)
    for (int k = 0; k < 4; ++k) {
      int flat = tid + 256*k;      // 1024 chunks of 8 floats
      int row  = flat >> 4;
      int c8   = flat & 15;
      const float* gp = x + ((size_t)row*II + i)*DD + c8*8;
      float4 f0 = *(const float4*)(gp);
      float4 f1 = *(const float4*)(gp + 4);
      float fv[8] = {f0.x,f0.y,f0.z,f0.w,f1.x,f1.y,f1.z,f1.w};
      ushort8 h, l;
      #pragma unroll
      for (int e = 0; e < 8; ++e) {
        ushort_t hh = f2bf(fv[e]); h[e] = hh; l[e] = f2bf(fv[e] - bf2f(hh));
      }
      int off = (row*256 + c8*16) ^ ((row & 7) << 4);
      *(ushort8*)((char*)Ah + off) = h;
      *(ushort8*)((char*)Al + off) = l;
    }

    #pragma unroll
    for (int j = 0; j < 4; ++j) {
      const int n = nj*4 + j;
      // stage B = W[n, i, :, :] (prev MFMA B-reads done via prev bar_B)
      const float* wbase = W + (((size_t)n*II + i)*OO)*DD;
      for (int k = 0; k < 4; ++k) {
        int flat = tid + 256*k;
        int row  = flat >> 4;
        int c8   = flat & 15;
        const float* gp = wbase + row*DD + c8*8;
        float4 f0 = *(const float4*)(gp);
        float4 f1 = *(const float4*)(gp + 4);
        float fv[8] = {f0.x,f0.y,f0.z,f0.w,f1.x,f1.y,f1.z,f1.w};
        ushort8 h, l;
        #pragma unroll
        for (int e = 0; e < 8; ++e) {
          ushort_t hh = f2bf(fv[e]); h[e] = hh; l[e] = f2bf(fv[e] - bf2f(hh));
        }
        int off = (row*256 + c8*16) ^ ((row & 7) << 4);
        *(ushort8*)((char*)Bh + off) = h;
        *(ushort8*)((char*)Bl + off) = l;
      }
      __syncthreads();   // A+B staged; prev j's Cs reads drained

      f32x4 zero = {0.f, 0.f, 0.f, 0.f};
      f32x4 acc[4];
      #pragma unroll
      for (int ot = 0; ot < 4; ++ot) acc[ot] = zero;

      #pragma unroll
      for (int kk = 0; kk < 4; ++kk) {
        int ra   = w*16 + (lane & 15);
        int aoff = (ra*256 + kk*64 + ((lane >> 4) << 4)) ^ ((ra & 7) << 4);
        bf16x8 ah = *(bf16x8*)((char*)Ah + aoff);
        bf16x8 al = *(bf16x8*)((char*)Al + aoff);
        #pragma unroll
        for (int ot = 0; ot < 4; ++ot) {
          int rb   = ot*16 + (lane & 15);
          int boff = (rb*256 + kk*64 + ((lane >> 4) << 4)) ^ ((rb & 7) << 4);
          bf16x8 bh = *(bf16x8*)((char*)Bh + boff);
          bf16x8 bl = *(bf16x8*)((char*)Bl + boff);
          acc[ot] = __builtin_amdgcn_mfma_f32_16x16x32_bf16(ah, bh, acc[ot], 0, 0, 0);
          acc[ot] = __builtin_amdgcn_mfma_f32_16x16x32_bf16(al, bh, acc[ot], 0, 0, 0);
          acc[ot] = __builtin_amdgcn_mfma_f32_16x16x32_bf16(ah, bl, acc[ot], 0, 0, 0);
        }
      }

      // D lane map: col = lane&15, row = (lane>>4)*4 + r  (m89-verified)
      #pragma unroll
      for (int ot = 0; ot < 4; ++ot) {
        acc0[j][ot] += acc[ot];          // fused round-0 accumulation
        #pragma unroll
        for (int r = 0; r < 4; ++r) {
          int row = w*16 + ((lane >> 4) << 2) + r;
          int col = ot*16 + (lane & 15);
          Cs[row*64 + col] = acc[ot][r];
        }
      }
      __syncthreads();   // Cs complete

      // coalesced store Cs -> u[b, n, i, :] as fp16
      for (int k = 0; k < 2; ++k) {
        int flat = tid + 256*k;
        int row  = flat >> 3;
        int c8   = flat & 7;
        const float* sp = Cs + row*64 + c8*8;
        half8 v;
        #pragma unroll
        for (int e = 0; e < 8; ++e) v[e] = (half_t)sp[e];
        *(half8*)(u + (((size_t)row*NN + n)*II + i)*OO + c8*8) = v;
      }
    }
  }

  // epilogue: acc0 -> part0[ic][b][n][o]
  #pragma unroll
  for (int j = 0; j < 4; ++j) {
    const int n = nj*4 + j;
    __syncthreads();   // prev Cs consumers done
    #pragma unroll
    for (int ot = 0; ot < 4; ++ot)
      #pragma unroll
      for (int r = 0; r < 4; ++r) {
        int row = w*16 + ((lane >> 4) << 2) + r;
        int col = ot*16 + (lane & 15);
        Cs[row*64 + col] = acc0[j][ot][r];
      }
    __syncthreads();
    for (int k = 0; k < 2; ++k) {
      int flat = tid + 256*k;   // 512 chunks of 8 floats
      int row  = flat >> 3;     // b
      int c8   = flat & 7;
      const float* sp = Cs + row*64 + c8*8;
      float* dst = part0 + (((size_t)ic*BB + row)*NN + n)*OO + c8*8;
      *(f32x4*)dst       = *(const f32x4*)sp;
      *(f32x4*)(dst + 4) = *(const f32x4*)(sp + 4);
    }
  }
}

// ---------------------------------------------------------------------------
// K2: out0[j] = (1/32) * sum_{ic<64} part0[ic][j]   (fixed order)
// ---------------------------------------------------------------------------
__global__ __launch_bounds__(256) void k_reduce0(
    const float* __restrict__ part0, float* __restrict__ out0)
{
  const int j = blockIdx.x*256 + threadIdx.x;   // grid = 512
  const size_t O = (size_t)BB*NN*OO;
  float s = 0.f;
  #pragma unroll
  for (int k = 0; k < 64; ++k) s += part0[(size_t)k*O + j];
  out0[j] = s * (1.f/32.f);
}

// ---------------------------------------------------------------------------
// K3: register-fused routing round — ONE pass over u per round.
// (validated rounds 5-6)
// ---------------------------------------------------------------------------
__global__ __launch_bounds__(256, 2) void k_round_reg(
    const half_t* __restrict__ u, const float* __restrict__ out_prev,
    float* __restrict__ part)
{
  __shared__ float sOut[NN*OO];        // 8 KB
  __shared__ float sP[NN][16][9];      // 18 KB (pad 9 kills 8-way conflicts)
  __shared__ float sLog[16][NN+1];
  __shared__ float sC[16][NN+1];
  const int tid = threadIdx.x;
  const int ic  = blockIdx.x;          // 0..7
  const int b   = blockIdx.y;
  const int n   = tid >> 3;
  const int q   = tid & 7;

  for (int k = 0; k < 8; ++k) {
    int flat = tid + 256*k;
    sOut[flat] = out_prev[(size_t)b*NN*OO + flat];
  }
  float a8[8];
  #pragma unroll
  for (int e = 0; e < 8; ++e) a8[e] = 0.f;
  __syncthreads();

  const half_t* ubase = u + ((size_t)b*NN + n)*II*OO;
  for (int s = 0; s < 4; ++s) {
    const int i0 = ic*64 + s*16;
    float r[16][8];
    // phase 1: load 16 i-rows' o-chunk into regs + partial logit dots
    #pragma unroll
    for (int ii = 0; ii < 16; ++ii) {
      load8u(ubase + (size_t)(i0+ii)*OO + q*8, r[ii]);
      float acc = 0.f;
      #pragma unroll
      for (int e = 0; e < 8; ++e) acc += r[ii][e] * sOut[n*OO + q*8 + e];
      sP[n][ii][q] = acc;
    }
    __syncthreads();
    // logits: thread handles ii = q and q+8
    #pragma unroll
    for (int h = 0; h < 2; ++h) {
      int ii = q + h*8;
      float sum = 0.f;
      #pragma unroll
      for (int q2 = 0; q2 < 8; ++q2) sum += sP[n][ii][q2];
      sLog[ii][n] = sum;
    }
    __syncthreads();
    // softmax over n (redundant, fixed order -> deterministic)
    #pragma unroll
    for (int h = 0; h < 2; ++h) {
      int ii = q + h*8;
      float m = -1e30f;
      #pragma unroll
      for (int n2 = 0; n2 < NN; ++n2) m = fmaxf(m, sLog[ii][n2]);
      float ss = 0.f;
      #pragma unroll
      for (int n2 = 0; n2 < NN; ++n2) ss += __expf(sLog[ii][n2] - m);
      sC[ii][n] = __expf(sLog[ii][n] - m) / ss;
    }
    __syncthreads();
    // phase 2: entirely from registers
    #pragma unroll
    for (int ii = 0; ii < 16; ++ii) {
      float cv = sC[ii][n];
      #pragma unroll
      for (int e = 0; e < 8; ++e) a8[e] += cv * r[ii][e];
    }
  }
  float* dst = part + (((size_t)ic*BB + b)*NN + n)*OO + q*8;
  #pragma unroll
  for (int e = 0; e < 8; ++e) dst[e] = a8[e];
}

// ---------------------------------------------------------------------------
// K3b: out_next[j] = sum_{k<8} part[k][j], fixed order.
// ---------------------------------------------------------------------------
__global__ __launch_bounds__(256) void k_reduce_part(
    const float* __restrict__ part, float* __restrict__ out_next)
{
  const int j = blockIdx.x*256 + threadIdx.x;   // grid = 512
  const size_t O = (size_t)BB*NN*OO;
  float s = 0.f;
  #pragma unroll
  for (int k = 0; k < 8; ++k) s += part[(size_t)k*O + j];
  out_next[j] = s;
}

// ---------------------------------------------------------------------------
// K4: lengths[b,n] = sqrt(sum_o out2^2)
// ---------------------------------------------------------------------------
__global__ __launch_bounds__(256) void k_len(
    const float* __restrict__ out2, float* __restrict__ dout)
{
  int t = blockIdx.x*blockDim.x + threadIdx.x;
  if (t < BB*NN) {
    const float* p = out2 + (size_t)t*OO;
    float s = 0.f;
    #pragma unroll
    for (int o = 0; o < OO; ++o) { float f = p[o]; s += f*f; }
    dout[t] = sqrtf(s);
  }
}

extern "C" void kernel_launch(void* const* d_in, const int* in_sizes, int n_in,
                              void* d_out, int out_size, void* d_ws, size_t ws_size,
                              hipStream_t stream)
{
  const float* x = (const float*)d_in[0];
  const float* W = (const float*)d_in[1];
  float* dout = (float*)d_out;

  const size_t U = (size_t)BB*NN*II*OO;   // 67,108,864 elements
  const size_t O = (size_t)BB*NN*OO;      // 131,072

  half_t* u    = (half_t*)d_ws;                     // 128 MiB fp16
  float* part0 = (float*)((char*)d_ws + U*2);       // 64*O floats = 32 MiB
  float* out0  = part0 + 64*O;
  float* out1  = out0 + O;
  float* out2  = out1 + O;
  float* part  = out2 + O;                          // 8*O floats = 4 MiB

  k_compute_u_r0<<<dim3(64, 8), dim3(256), 0, stream>>>(x, W, u, part0);
  k_reduce0     <<<dim3(512),   dim3(256), 0, stream>>>(part0, out0);
  k_round_reg   <<<dim3(8, BB), dim3(256), 0, stream>>>(u, out0, part);
  k_reduce_part <<<dim3(512),   dim3(256), 0, stream>>>(part, out1);
  k_round_reg   <<<dim3(8, BB), dim3(256), 0, stream>>>(u, out1, part);
  k_reduce_part <<<dim3(512),   dim3(256), 0, stream>>>(part, out2);
  hipLaunchKernelGGL(k_len, dim3(8), dim3(256), 0, stream, out2, dout);
}

// Round 8
// 212.609 us; speedup vs baseline: 1.3274x; 1.3274x over previous
//
#include <hip/hip_runtime.h>

typedef unsigned short ushort_t;
typedef _Float16 half_t;
typedef __attribute__((ext_vector_type(8))) unsigned short ushort8;
typedef __attribute__((ext_vector_type(8))) _Float16 half8;
typedef __attribute__((ext_vector_type(4))) float f32x4;

#define BB 64
#define II 512
#define DD 128
#define NN 32
#define OO 64

// load 8 contiguous u-elements (fp16) as fp32
__device__ inline void load8u(const half_t* p, float* a) {
  half8 v = *(const half8*)p;
  #pragma unroll
  for (int e = 0; e < 8; ++e) a[e] = (float)v[e];
}

// ---------------------------------------------------------------------------
// K1: u[b,n,i,o] = sum_d x[b,i,d] * W[n,i,o,d] via single fp16 MFMA
// (f32->f16 input rounding err 2^-12; measured bf16-both = 9.16 absmax at
// 2^-9 -> linear scaling predicts ~1.15 here; fp16-u storage adds ~1.5).
// WG = (i, n-block of 8), structure identical to validated round-6 kernel;
// LDS 48 KB -> 3 blocks/CU. XOR-swizzle ((row&7)<<4) on 256B rows.
// ---------------------------------------------------------------------------
__global__ __launch_bounds__(256) void k_compute_u(
    const float* __restrict__ x, const float* __restrict__ W,
    half_t* __restrict__ u)
{
  __shared__ half_t As[64*128] __attribute__((aligned(16)));
  __shared__ half_t Bs[64*128] __attribute__((aligned(16)));
  __shared__ float  Cs[64*64]  __attribute__((aligned(16)));
  const int tid  = threadIdx.x;
  const int i    = blockIdx.x;
  const int n0   = blockIdx.y * 8;
  const int w    = tid >> 6;
  const int lane = tid & 63;

  // stage A = x[:, i, :]  (64 b-rows x 128 d), fp32 -> fp16
  for (int k = 0; k < 4; ++k) {
    int flat = tid + 256*k;      // 1024 chunks of 8 floats
    int row  = flat >> 4;
    int c8   = flat & 15;
    const float* gp = x + ((size_t)row*II + i)*DD + c8*8;
    float4 f0 = *(const float4*)(gp);
    float4 f1 = *(const float4*)(gp + 4);
    half8 v;
    v[0]=(half_t)f0.x; v[1]=(half_t)f0.y; v[2]=(half_t)f0.z; v[3]=(half_t)f0.w;
    v[4]=(half_t)f1.x; v[5]=(half_t)f1.y; v[6]=(half_t)f1.z; v[7]=(half_t)f1.w;
    int off = (row*256 + c8*16) ^ ((row & 7) << 4);
    *(half8*)((char*)As + off) = v;
  }

  for (int j = 0; j < 8; ++j) {
    int n = n0 + j;
    __syncthreads();  // A staged (j==0); prev iter's Cs->u store done (j>0)

    // stage B = W[n, i, :, :]  (64 o-rows x 128 d), fp32 -> fp16
    const float* wbase = W + (((size_t)n*II + i)*OO)*DD;
    for (int k = 0; k < 4; ++k) {
      int flat = tid + 256*k;
      int row  = flat >> 4;
      int c8   = flat & 15;
      const float* gp = wbase + row*DD + c8*8;
      float4 f0 = *(const float4*)(gp);
      float4 f1 = *(const float4*)(gp + 4);
      half8 v;
      v[0]=(half_t)f0.x; v[1]=(half_t)f0.y; v[2]=(half_t)f0.z; v[3]=(half_t)f0.w;
      v[4]=(half_t)f1.x; v[5]=(half_t)f1.y; v[6]=(half_t)f1.z; v[7]=(half_t)f1.w;
      int off = (row*256 + c8*16) ^ ((row & 7) << 4);
      *(half8*)((char*)Bs + off) = v;
    }
    __syncthreads();

    f32x4 zero = {0.f, 0.f, 0.f, 0.f};
    f32x4 acc[4];
    #pragma unroll
    for (int ot = 0; ot < 4; ++ot) acc[ot] = zero;

    // wave w owns b-rows [16w,16w+16); A lane: m=lane&15, k=(lane>>4)*8+e
    #pragma unroll
    for (int kk = 0; kk < 4; ++kk) {
      int ra   = w*16 + (lane & 15);
      int aoff = (ra*256 + kk*64 + ((lane >> 4) << 4)) ^ ((ra & 7) << 4);
      half8 av = *(half8*)((char*)As + aoff);
      #pragma unroll
      for (int ot = 0; ot < 4; ++ot) {
        int rb   = ot*16 + (lane & 15);
        int boff = (rb*256 + kk*64 + ((lane >> 4) << 4)) ^ ((rb & 7) << 4);
        half8 bv = *(half8*)((char*)Bs + boff);
        acc[ot] = __builtin_amdgcn_mfma_f32_16x16x32_f16(av, bv, acc[ot], 0, 0, 0);
      }
    }

    // D lane map: col = lane&15, row = (lane>>4)*4 + r  (m89-verified,
    // dtype-independent)
    #pragma unroll
    for (int ot = 0; ot < 4; ++ot)
      #pragma unroll
      for (int r = 0; r < 4; ++r) {
        int row = w*16 + ((lane >> 4) << 2) + r;
        int col = ot*16 + (lane & 15);
        Cs[row*64 + col] = acc[ot][r];
      }
    __syncthreads();

    // coalesced store Cs -> u[b, n, i, :] as fp16
    for (int k = 0; k < 2; ++k) {
      int flat = tid + 256*k;   // 512 chunks of 8
      int row  = flat >> 3;     // b
      int c8   = flat & 7;
      const float* sp = Cs + row*64 + c8*8;
      half8 v;
      #pragma unroll
      for (int e = 0; e < 8; ++e) v[e] = (half_t)sp[e];
      *(half8*)(u + (((size_t)row*NN + n)*II + i)*OO + c8*8) = v;
    }
  }
}

// ---------------------------------------------------------------------------
// K2: out0[b,n,o] = (1/32) * sum_i u[b,n,i,o]   (round 0: c uniform)
// (validated rounds 3-6)
// ---------------------------------------------------------------------------
__global__ __launch_bounds__(256) void k_round0(
    const half_t* __restrict__ u, float* __restrict__ out0)
{
  __shared__ float sPart[32*65];
  const int tid = threadIdx.x;
  const int bn  = blockIdx.x;          // b*32+n
  const int ip  = tid >> 3;
  const int o8  = tid & 7;
  const half_t* base = u + (size_t)bn * (II*OO);
  float a[8];
  #pragma unroll
  for (int e = 0; e < 8; ++e) a[e] = 0.f;
  for (int i = ip; i < II; i += 32) {
    float t[8];
    load8u(base + (size_t)i*OO + o8*8, t);
    #pragma unroll
    for (int e = 0; e < 8; ++e) a[e] += t[e];
  }
  #pragma unroll
  for (int e = 0; e < 8; ++e) sPart[ip*65 + o8*8 + e] = a[e];
  for (int step = 16; step >= 1; step >>= 1) {
    __syncthreads();
    if (ip < step) {
      #pragma unroll
      for (int e = 0; e < 8; ++e)
        sPart[ip*65 + o8*8 + e] += sPart[(ip+step)*65 + o8*8 + e];
    }
  }
  __syncthreads();
  if (tid < 64) out0[(size_t)bn*OO + tid] = sPart[tid] * (1.f/32.f);
}

// ---------------------------------------------------------------------------
// K3: register-fused routing round — ONE pass over u per round.
// (validated rounds 5-6)
// ---------------------------------------------------------------------------
__global__ __launch_bounds__(256, 2) void k_round_reg(
    const half_t* __restrict__ u, const float* __restrict__ out_prev,
    float* __restrict__ part)
{
  __shared__ float sOut[NN*OO];        // 8 KB
  __shared__ float sP[NN][16][9];      // 18 KB (pad 9 kills 8-way conflicts)
  __shared__ float sLog[16][NN+1];
  __shared__ float sC[16][NN+1];
  const int tid = threadIdx.x;
  const int ic  = blockIdx.x;          // 0..7
  const int b   = blockIdx.y;
  const int n   = tid >> 3;
  const int q   = tid & 7;

  for (int k = 0; k < 8; ++k) {
    int flat = tid + 256*k;
    sOut[flat] = out_prev[(size_t)b*NN*OO + flat];
  }
  float a8[8];
  #pragma unroll
  for (int e = 0; e < 8; ++e) a8[e] = 0.f;
  __syncthreads();

  const half_t* ubase = u + ((size_t)b*NN + n)*II*OO;
  for (int s = 0; s < 4; ++s) {
    const int i0 = ic*64 + s*16;
    float r[16][8];
    // phase 1: load 16 i-rows' o-chunk into regs + partial logit dots
    #pragma unroll
    for (int ii = 0; ii < 16; ++ii) {
      load8u(ubase + (size_t)(i0+ii)*OO + q*8, r[ii]);
      float acc = 0.f;
      #pragma unroll
      for (int e = 0; e < 8; ++e) acc += r[ii][e] * sOut[n*OO + q*8 + e];
      sP[n][ii][q] = acc;
    }
    __syncthreads();
    // logits: thread handles ii = q and q+8
    #pragma unroll
    for (int h = 0; h < 2; ++h) {
      int ii = q + h*8;
      float sum = 0.f;
      #pragma unroll
      for (int q2 = 0; q2 < 8; ++q2) sum += sP[n][ii][q2];
      sLog[ii][n] = sum;
    }
    __syncthreads();
    // softmax over n (redundant, fixed order -> deterministic)
    #pragma unroll
    for (int h = 0; h < 2; ++h) {
      int ii = q + h*8;
      float m = -1e30f;
      #pragma unroll
      for (int n2 = 0; n2 < NN; ++n2) m = fmaxf(m, sLog[ii][n2]);
      float ss = 0.f;
      #pragma unroll
      for (int n2 = 0; n2 < NN; ++n2) ss += __expf(sLog[ii][n2] - m);
      sC[ii][n] = __expf(sLog[ii][n] - m) / ss;
    }
    __syncthreads();
    // phase 2: entirely from registers
    #pragma unroll
    for (int ii = 0; ii < 16; ++ii) {
      float cv = sC[ii][n];
      #pragma unroll
      for (int e = 0; e < 8; ++e) a8[e] += cv * r[ii][e];
    }
  }
  float* dst = part + (((size_t)ic*BB + b)*NN + n)*OO + q*8;
  #pragma unroll
  for (int e = 0; e < 8; ++e) dst[e] = a8[e];
}

// ---------------------------------------------------------------------------
// K3b: out_next[j] = sum_{k<8} part[k][j], fixed order.
// ---------------------------------------------------------------------------
__global__ __launch_bounds__(256) void k_reduce_part(
    const float* __restrict__ part, float* __restrict__ out_next)
{
  const int j = blockIdx.x*256 + threadIdx.x;   // grid = 512
  const size_t O = (size_t)BB*NN*OO;
  float s = 0.f;
  #pragma unroll
  for (int k = 0; k < 8; ++k) s += part[(size_t)k*O + j];
  out_next[j] = s;
}

// ---------------------------------------------------------------------------
// K4: fused final reduce + lengths:
//  out2[b,n,o] = sum_{k<8} part[k][b,n,o];  dout[b,n] = sqrt(sum_o out2^2)
//  1 wave per (b,n); fixed-order sums + wave shuffle reduce (deterministic).
// ---------------------------------------------------------------------------
__global__ __launch_bounds__(64) void k_reduce_len(
    const float* __restrict__ part, float* __restrict__ dout)
{
  const int bn = blockIdx.x;           // 0 .. B*N-1
  const int o  = threadIdx.x;          // 0..63
  const size_t O = (size_t)BB*NN*OO;
  float s = 0.f;
  #pragma unroll
  for (int k = 0; k < 8; ++k) s += part[(size_t)k*O + (size_t)bn*OO + o];
  float sq = s * s;
  #pragma unroll
  for (int d = 32; d >= 1; d >>= 1) sq += __shfl_xor(sq, d, 64);
  if (o == 0) dout[bn] = sqrtf(sq);
}

extern "C" void kernel_launch(void* const* d_in, const int* in_sizes, int n_in,
                              void* d_out, int out_size, void* d_ws, size_t ws_size,
                              hipStream_t stream)
{
  const float* x = (const float*)d_in[0];
  const float* W = (const float*)d_in[1];
  float* dout = (float*)d_out;

  const size_t U = (size_t)BB*NN*II*OO;   // 67,108,864 elements
  const size_t O = (size_t)BB*NN*OO;      // 131,072

  half_t* u   = (half_t*)d_ws;                      // 128 MiB fp16
  float* out0 = (float*)((char*)d_ws + U*2);
  float* out1 = out0 + O;
  float* part = out1 + O;                           // 8*O floats = 4 MiB

  k_compute_u  <<<dim3(II, 4),  dim3(256), 0, stream>>>(x, W, u);
  k_round0     <<<dim3(BB*NN),  dim3(256), 0, stream>>>(u, out0);
  k_round_reg  <<<dim3(8, BB),  dim3(256), 0, stream>>>(u, out0, part);
  k_reduce_part<<<dim3(512),    dim3(256), 0, stream>>>(part, out1);
  k_round_reg  <<<dim3(8, BB),  dim3(256), 0, stream>>>(u, out1, part);
  k_reduce_len <<<dim3(BB*NN),  dim3(64),  0, stream>>>(part, dout);
}